// Round 7
// baseline (264.221 us; speedup 1.0000x reference)
//
#include <hip/hip_runtime.h>
#include <hip/hip_bf16.h>

#define D 128
#define EPSV 1e-5f

static inline int cdiv(int a, int b) { return (a + b - 1) / b; }

typedef __attribute__((ext_vector_type(8))) short short8v;
typedef __attribute__((ext_vector_type(4))) float floatx4;

// bf16 RNE pack / unpack helpers
__device__ __forceinline__ unsigned short f2bf(float f) {
    unsigned int x = __float_as_uint(f);
    unsigned int r = x + 0x7fffu + ((x >> 16) & 1u);
    return (unsigned short)(r >> 16);
}
__device__ __forceinline__ float bflo(unsigned int u) { return __uint_as_float(u << 16); }
__device__ __forceinline__ float bfhi(unsigned int u) {
    return __uint_as_float(u & 0xffff0000u);
}

// ---------------- W -> bf16 transposed + cnt zeroing (once per launch) ----------------

__global__ void prep_w(const float* __restrict__ W1, const float* __restrict__ W2,
                       unsigned short* __restrict__ WT1, unsigned short* __restrict__ WT2,
                       int* __restrict__ cnt, int N) {
    int b = blockIdx.x;
    const float* W = (b < D) ? W1 : W2;
    unsigned short* WT = (b < D) ? WT1 : WT2;
    int k = b & (D - 1);
    int n = threadIdx.x;
    WT[n * D + k] = f2bf(W[k * D + n]);
    int gid = b * D + n;
    for (int i = gid; i < N; i += 2 * D * D) cnt[i] = 0;
}

// ---------------- hist + layer-1 BN stats + per-graph softmax stats -------------------
// blocks [0,HB): edge histogram + arrival rank (atomic-bound, low BW).
// blocks [HB,HB+NB): emb-gather BN partials (memory-bound) — exact bn_stats numerics.
// blocks [HB+NB,HB+NB+G): per-graph softmax m/s + bounds (depends only on tfidf/batch).
// m is exact (max order-insensitive); s reorder only enters pool's FINAL division.

__global__ __launch_bounds__(256) void hist_bn_kernel(
    const int* __restrict__ col, int* __restrict__ cnt, int* __restrict__ rank, int E_,
    const float* __restrict__ emb, const int* __restrict__ idx,
    float* __restrict__ pS, float* __restrict__ pQ, int n, int HB, int NB,
    const float* __restrict__ tfidf, const int* __restrict__ batch,
    float* __restrict__ gm, float* __restrict__ gs, int* __restrict__ gb, int G_) {
    int tid = threadIdx.x;
    if ((int)blockIdx.x < HB) {
        int e = blockIdx.x * 256 + tid;
        if (e < E_) rank[e] = atomicAdd(&cnt[col[e]], 1);
        return;
    }
    int bid = blockIdx.x - HB;
    if (bid >= NB) {
        // ---- per-graph softmax stats ----
        int g = bid - NB;
        __shared__ int sb2[2];
        if (tid < 2) {
            int target = g + tid;
            int lo = 0, hi = n;
            while (lo < hi) {
                int mid = (lo + hi) >> 1;
                if (batch[mid] < target) lo = mid + 1;
                else hi = mid;
            }
            sb2[tid] = lo;
        }
        __syncthreads();
        int s0 = sb2[0], s1 = sb2[1];
        __shared__ float red[256];
        float m = -1e30f;
        for (int i = s0 + tid; i < s1; i += 256) m = fmaxf(m, tfidf[i]);
        red[tid] = m;
        __syncthreads();
        for (int off = 128; off > 0; off >>= 1) {
            if (tid < off) red[tid] = fmaxf(red[tid], red[tid + off]);
            __syncthreads();
        }
        m = red[0];
        __syncthreads();
        float s = 0.f;
        for (int i = s0 + tid; i < s1; i += 256) s += __expf(tfidf[i] - m);
        red[tid] = s;
        __syncthreads();
        for (int off = 128; off > 0; off >>= 1) {
            if (tid < off) red[tid] += red[tid + off];
            __syncthreads();
        }
        if (tid == 0) {
            gm[g] = m;
            gs[g] = red[0];
            gb[g] = s0;
            if (g == G_ - 1) gb[G_] = s1;
        }
        return;
    }
    // ---- bn-stats path (layer 1: emb gather; exact bn_stats numerics) ----
    int sub = tid >> 5;
    int q = tid & 31;
    float4 s = make_float4(0, 0, 0, 0), s2 = make_float4(0, 0, 0, 0);
    int stride = NB * 8;
    int i = bid * 8 + sub;
    int r_next = (i < n) ? idx[i] : 0;
    for (; i < n; i += stride) {
        int r = r_next;
        int i2 = i + stride;
        if (i2 < n) r_next = idx[i2];
        float4 v = *(const float4*)&emb[(long)r * D + q * 4];
        s.x += v.x; s.y += v.y; s.z += v.z; s.w += v.w;
        s2.x += v.x * v.x; s2.y += v.y * v.y; s2.z += v.z * v.z; s2.w += v.w * v.w;
    }
    __shared__ float4 redA[256], redB[256];
    redA[tid] = s;
    redB[tid] = s2;
    __syncthreads();
    for (int off = 128; off >= 32; off >>= 1) {
        if (tid < off) {
            float4 a = redA[tid + off], b = redB[tid + off];
            redA[tid].x += a.x; redA[tid].y += a.y;
            redA[tid].z += a.z; redA[tid].w += a.w;
            redB[tid].x += b.x; redB[tid].y += b.y;
            redB[tid].z += b.z; redB[tid].w += b.w;
        }
        __syncthreads();
    }
    if (tid < 32) {
        float4 a = redA[tid], b = redB[tid];
        int bofs = bid;
        pS[(q * 4 + 0) * NB + bofs] = a.x;
        pS[(q * 4 + 1) * NB + bofs] = a.y;
        pS[(q * 4 + 2) * NB + bofs] = a.z;
        pS[(q * 4 + 3) * NB + bofs] = a.w;
        pQ[(q * 4 + 0) * NB + bofs] = b.x;
        pQ[(q * 4 + 1) * NB + bofs] = b.y;
        pQ[(q * 4 + 2) * NB + bofs] = b.z;
        pQ[(q * 4 + 3) * NB + bofs] = b.w;
    }
}

// ---------------- scan + layer-1 BN reduce (one dispatch) ----------------

__global__ void scan_bnred_kernel(const int* __restrict__ cnt, int* __restrict__ offs,
                                  int n, int E_, int nbk,
                                  const float* __restrict__ pS, const float* __restrict__ pQ,
                                  int nb2, const float* __restrict__ gamma,
                                  const float* __restrict__ beta, float* __restrict__ scale,
                                  float* __restrict__ shift, float nn) {
    int tid = threadIdx.x;
    if ((int)blockIdx.x >= nbk) {
        int d = blockIdx.x - nbk;
        __shared__ float smS[256], smQ[256];
        if (tid < 256) {
            float s = 0.f, q = 0.f;
            for (int b = tid; b < nb2; b += 256) {
                s += pS[d * nb2 + b];
                q += pQ[d * nb2 + b];
            }
            smS[tid] = s;
            smQ[tid] = q;
        }
        __syncthreads();
        for (int off = 128; off > 0; off >>= 1) {
            if (tid < off) {
                smS[tid] += smS[tid + off];
                smQ[tid] += smQ[tid + off];
            }
            __syncthreads();
        }
        if (tid == 0) {
            float mean = smS[0] / nn;
            float var = smQ[0] / nn - mean * mean;
            float rstd = rsqrtf(var + EPSV);
            float sc = gamma[d] * rstd;
            scale[d] = sc;
            shift[d] = beta[d] - mean * sc;
        }
        return;
    }
    __shared__ int sm[1024];
    __shared__ int sbo_s;
    int lim = blockIdx.x * 1024;
    int pre = 0;
    for (int i = tid; i < lim; i += 1024) pre += cnt[i];
    sm[tid] = pre;
    __syncthreads();
    for (int off = 512; off > 0; off >>= 1) {
        if (tid < off) sm[tid] += sm[tid + off];
        __syncthreads();
    }
    if (tid == 0) {
        sbo_s = sm[0];
        if (blockIdx.x == 0) offs[n] = E_;
    }
    __syncthreads();
    int i = lim + tid;
    int v = (i < n) ? cnt[i] : 0;
    sm[tid] = v;
    __syncthreads();
    for (int off = 1; off < 1024; off <<= 1) {
        int t = (tid >= off) ? sm[tid - off] : 0;
        __syncthreads();
        sm[tid] += t;
        __syncthreads();
    }
    if (i < n) offs[i] = sm[tid] - v + sbo_s;
}

// scatter packed (src_row<<32 | ea_bits) into CSR slot offs[col]+rank.
__global__ void scatter_pack(const int* __restrict__ row, const int* __restrict__ col,
                             const float* __restrict__ ea, const int* __restrict__ rank,
                             const int* __restrict__ offs, long long* __restrict__ pk,
                             int E_) {
    int e = blockIdx.x * blockDim.x + threadIdx.x;
    if (e >= E_) return;
    int p = offs[col[e]] + rank[e];
    pk[p] = ((long long)row[e] << 32) | (unsigned int)__float_as_int(ea[e]);
}

// ---------------- degree-adaptive sort (unchanged from round-6 PASS) ----------------

__global__ __launch_bounds__(256) void sort_deg_kernel(const long long* __restrict__ pk,
                                                       const int* __restrict__ offs,
                                                       float* __restrict__ dis,
                                                       int2* __restrict__ csr, int n) {
    int w = blockIdx.x * 4 + (threadIdx.x >> 6);
    int lane = threadIdx.x & 63;
    int n0 = w * 4;
    if (n0 >= n) return;
    int g = lane >> 4;
    int node_q = n0 + g;
    int p0q = 0, degq = 0;
    if (node_q < n) {
        p0q = offs[node_q];
        degq = offs[node_q + 1] - p0q;
    }
    int dmax = degq;
    dmax = max(dmax, __shfl_xor(dmax, 16, 64));
    dmax = max(dmax, __shfl_xor(dmax, 32, 64));
    if (dmax <= 16) {
        int sub = lane & 15;
        long long v = (sub < degq) ? pk[p0q + sub] : 0x7fffffffffffffffLL;
        for (int k = 2; k <= 16; k <<= 1) {
            for (int j = k >> 1; j > 0; j >>= 1) {
                long long partner = __shfl_xor(v, j, 64);
                bool up = ((sub & k) == 0);
                bool keepMin = ((sub & j) == 0);
                long long mn = v < partner ? v : partner;
                long long mx = v < partner ? partner : v;
                v = (up == keepMin) ? mn : mx;
            }
        }
        int r = (int)(v >> 32);
        int eab = (int)(v & 0xffffffffLL);
        if (sub < degq) csr[p0q + sub] = make_int2(r, eab);
        float av = (sub < degq) ? __int_as_float(eab) : 0.f;
        float s = av;
        for (int off = 8; off > 0; off >>= 1) s += __shfl_xor(s, off, 64);
        if (sub == 0 && node_q < n) dis[node_q] = s > 0.f ? rsqrtf(fmaxf(s, EPSV)) : 0.f;
        return;
    }
    int h = lane >> 5;
    int sub5 = lane & 31;
    for (int pass = 0; pass < 2; ++pass) {
        int node_d = n0 + pass * 2 + h;
        int p0d = 0, degd = 0;
        if (node_d < n) {
            p0d = offs[node_d];
            degd = offs[node_d + 1] - p0d;
        }
        int pmax = max(degd, __shfl_xor(degd, 32, 64));
        if (pmax <= 32) {
            long long v = (sub5 < degd) ? pk[p0d + sub5] : 0x7fffffffffffffffLL;
            for (int k = 2; k <= 32; k <<= 1) {
                for (int j = k >> 1; j > 0; j >>= 1) {
                    long long partner = __shfl_xor(v, j, 64);
                    bool up = ((sub5 & k) == 0);
                    bool keepMin = ((sub5 & j) == 0);
                    long long mn = v < partner ? v : partner;
                    long long mx = v < partner ? partner : v;
                    v = (up == keepMin) ? mn : mx;
                }
            }
            int r = (int)(v >> 32);
            int eab = (int)(v & 0xffffffffLL);
            if (sub5 < degd) csr[p0d + sub5] = make_int2(r, eab);
            float av = (sub5 < degd) ? __int_as_float(eab) : 0.f;
            float s = av;
            for (int off = 16; off > 0; off >>= 1) s += __shfl_xor(s, off, 64);
            if (sub5 == 0 && node_d < n) dis[node_d] = s > 0.f ? rsqrtf(fmaxf(s, EPSV)) : 0.f;
        } else {
            for (int qq = 0; qq < 2; ++qq) {
                int node = n0 + pass * 2 + qq;
                if (node >= n) continue;
                int p0 = offs[node], p1 = offs[node + 1];
                int deg = p1 - p0;
                if (deg <= 64) {
                    long long v = (lane < deg) ? pk[p0 + lane] : 0x7fffffffffffffffLL;
                    for (int k = 2; k <= 64; k <<= 1) {
                        for (int j = k >> 1; j > 0; j >>= 1) {
                            long long partner = __shfl_xor(v, j, 64);
                            bool up = ((lane & k) == 0);
                            bool keepMin = ((lane & j) == 0);
                            long long mn = v < partner ? v : partner;
                            long long mx = v < partner ? partner : v;
                            v = (up == keepMin) ? mn : mx;
                        }
                    }
                    int r = (int)(v >> 32);
                    int eab = (int)(v & 0xffffffffLL);
                    if (lane < deg) csr[p0 + lane] = make_int2(r, eab);
                    float av = (lane < deg) ? __int_as_float(eab) : 0.f;
                    float s = av;
                    for (int off = 32; off > 0; off >>= 1) s += __shfl_xor(s, off, 64);
                    if (lane == 0) dis[node] = s > 0.f ? rsqrtf(fmaxf(s, EPSV)) : 0.f;
                } else {
                    if (lane == 0) {  // deterministic O(d^2) selection fallback
                        float dg = 0.f;
                        for (int p = p0; p < p1; ++p) {
                            long long best = 0x7fffffffffffffffLL;
                            for (int q2 = p0; q2 < p1; ++q2) {
                                long long cand = pk[q2];
                                int less = 0;
                                for (int q3 = p0; q3 < p1; ++q3)
                                    if (pk[q3] < cand) ++less;
                                if (less == p - p0) { best = cand; break; }
                            }
                            int r = (int)(best >> 32);
                            int eab = (int)(best & 0xffffffffLL);
                            csr[p] = make_int2(r, eab);
                            dg += __int_as_float(eab);
                        }
                        dis[node] = dg > 0.f ? rsqrtf(fmaxf(dg, EPSV)) : 0.f;
                    }
                }
            }
        }
    }
}

__global__ __launch_bounds__(256) void bn_reduce(const float* __restrict__ pS,
                                                 const float* __restrict__ pQ, int nb,
                                                 const float* __restrict__ gamma,
                                                 const float* __restrict__ beta,
                                                 float* __restrict__ scale,
                                                 float* __restrict__ shift, float n) {
    int d = blockIdx.x;
    int tid = threadIdx.x;
    float s = 0.f, q = 0.f;
    for (int b = tid; b < nb; b += 256) {
        s += pS[d * nb + b];
        q += pQ[d * nb + b];
    }
    __shared__ float smS[256], smQ[256];
    smS[tid] = s;
    smQ[tid] = q;
    __syncthreads();
    for (int off = 128; off > 0; off >>= 1) {
        if (tid < off) {
            smS[tid] += smS[tid + off];
            smQ[tid] += smQ[tid + off];
        }
        __syncthreads();
    }
    if (tid == 0) {
        float mean = smS[0] / n;
        float var = smQ[0] / n - mean * mean;
        float rstd = rsqrtf(var + EPSV);
        float sc = gamma[d] * rstd;
        scale[d] = sc;
        shift[d] = beta[d] - mean * sc;
    }
}

// ---------------- MFMA GEMM: h' = dis[r] * (bn(src) @ W), out bf16 ----------

template <bool GATHER, bool BF16IN>
__global__ __launch_bounds__(256) void gemm_mfma(const void* __restrict__ srcv,
                                                 const int* __restrict__ idx,
                                                 const float* __restrict__ scale,
                                                 const float* __restrict__ shift,
                                                 const unsigned short* __restrict__ WTb,
                                                 const float* __restrict__ disv,
                                                 unsigned short* __restrict__ outb, int n) {
    __shared__ unsigned short xsb[64 * 136];   // 17.0 KB
    __shared__ unsigned short wsb[128 * 136];  // 34.0 KB (reused as float scratch in epi)
    int tid = threadIdx.x;
    int r0 = blockIdx.x * 64;
    const float4* scale4 = (const float4*)scale;
    const float4* shift4 = (const float4*)shift;
    for (int it = 0; it < 4; ++it) {
        int flat = it * 256 + tid;  // 0..1023
        int r = flat >> 4;
        int c16 = flat & 15;
        int gr = r0 + r;
        float4 v0 = make_float4(0, 0, 0, 0), v1 = make_float4(0, 0, 0, 0);
        if (gr < n) {
            int srow = GATHER ? idx[gr] : gr;
            float4 x0, x1;
            if (BF16IN) {
                const unsigned short* sb = (const unsigned short*)srcv;
                uint4 raw = *(const uint4*)&sb[(long)srow * D + c16 * 8];
                x0 = make_float4(bflo(raw.x), bfhi(raw.x), bflo(raw.y), bfhi(raw.y));
                x1 = make_float4(bflo(raw.z), bfhi(raw.z), bflo(raw.w), bfhi(raw.w));
            } else {
                const float* sf = (const float*)srcv;
                x0 = *(const float4*)&sf[(long)srow * D + c16 * 8];
                x1 = *(const float4*)&sf[(long)srow * D + c16 * 8 + 4];
            }
            float4 sa = scale4[c16 * 2], sb2 = shift4[c16 * 2];
            float4 sc = scale4[c16 * 2 + 1], sd = shift4[c16 * 2 + 1];
            v0 = make_float4(x0.x * sa.x + sb2.x, x0.y * sa.y + sb2.y, x0.z * sa.z + sb2.z,
                             x0.w * sa.w + sb2.w);
            v1 = make_float4(x1.x * sc.x + sd.x, x1.y * sc.y + sd.y, x1.z * sc.z + sd.z,
                             x1.w * sc.w + sd.w);
        }
        int phys = c16 ^ (r & 15);
        ushort4 o0 = make_ushort4(f2bf(v0.x), f2bf(v0.y), f2bf(v0.z), f2bf(v0.w));
        ushort4 o1 = make_ushort4(f2bf(v1.x), f2bf(v1.y), f2bf(v1.z), f2bf(v1.w));
        *(ushort4*)&xsb[r * 136 + phys * 8] = o0;
        *(ushort4*)&xsb[r * 136 + phys * 8 + 4] = o1;
    }
    for (int it = 0; it < 8; ++it) {
        int flat = it * 256 + tid;  // 0..2047
        int nrow = flat >> 4;
        int c16 = flat & 15;
        int phys = c16 ^ (nrow & 15);
        uint4 w = *(const uint4*)&WTb[nrow * D + c16 * 8];
        *(uint4*)&wsb[nrow * 136 + phys * 8] = w;
    }
    __syncthreads();
    int wv = tid >> 6;
    int lane = tid & 63;
    int m = lane & 15, q = lane >> 4;
    int r0w = wv * 16;
    floatx4 acc[8];
#pragma unroll
    for (int t = 0; t < 8; ++t) acc[t] = (floatx4)(0.f);
#pragma unroll
    for (int ks = 0; ks < 4; ++ks) {
        int c16 = ks * 4 + q;
        short8v a = *(short8v*)&xsb[(r0w + m) * 136 + (c16 ^ ((r0w + m) & 15)) * 8];
#pragma unroll
        for (int t = 0; t < 8; ++t) {
            short8v b = *(short8v*)&wsb[(t * 16 + m) * 136 + (c16 ^ m) * 8];
            acc[t] = __builtin_amdgcn_mfma_f32_16x16x32_bf16(a, b, acc[t], 0, 0, 0);
        }
    }
    __syncthreads();
    float* fl = (float*)wsb;  // 64 x 132 floats
#pragma unroll
    for (int t = 0; t < 8; ++t) {
#pragma unroll
        for (int r = 0; r < 4; ++r) {
            fl[(r0w + q * 4 + r) * 132 + t * 16 + m] = acc[t][r];
        }
    }
    __syncthreads();
    for (int it = 0; it < 4; ++it) {
        int c = it * 256 + tid;
        int r = c >> 4;
        int k8 = (c & 15) * 8;
        int gr = r0 + r;
        if (gr < n) {
            float dsc = disv[gr];  // fold dis[row] into h' (removes fill_w)
            float4 v0 = *(float4*)&fl[r * 132 + k8];
            float4 v1 = *(float4*)&fl[r * 132 + k8 + 4];
            ushort4 o0 = make_ushort4(f2bf(v0.x * dsc), f2bf(v0.y * dsc), f2bf(v0.z * dsc),
                                      f2bf(v0.w * dsc));
            ushort4 o1 = make_ushort4(f2bf(v1.x * dsc), f2bf(v1.y * dsc), f2bf(v1.z * dsc),
                                      f2bf(v1.w * dsc));
            *(ushort4*)&outb[(long)gr * D + k8] = o0;
            *(ushort4*)&outb[(long)gr * D + k8 + 4] = o1;
        }
    }
}

// ---------------- dual-node aggregation body (math unchanged from round-4/5/6 PASS) ---
// NUMERICS: per node, even/odd-half partition + ascending edge order per half are
// bit-identical to the verified baseline (absmax 2^-9). Do NOT change the partition.

#define AGG_USTEP(acc_, e_, cnt_, UU)                                   \
    {                                                                   \
        int jj = j + 2 * (UU) + half;                                   \
        bool ok = jj < (cnt_);                                          \
        int sel = ok ? jj : 0;                                          \
        int r = __shfl((e_).x, sel, 64);                                \
        float w = ok ? __int_as_float(__shfl((e_).y, sel, 64)) : 0.f;   \
        uint2 uu = hw2[(long)r * 32 + fl];                              \
        (acc_).x += w * bflo(uu.x);                                     \
        (acc_).y += w * bfhi(uu.x);                                     \
        (acc_).z += w * bflo(uu.y);                                     \
        (acc_).w += w * bfhi(uu.y);                                     \
    }

__device__ __forceinline__ void agg_node_dual(const uint2* __restrict__ hw2,
                                              const int2* __restrict__ csr,
                                              const int* __restrict__ offs,
                                              const float* __restrict__ dis, float4 bs,
                                              int nodeA, int nodeB, int n, int lane,
                                              int half, int fl, float4& xA, float4& xB,
                                              bool& aAct, bool& bAct) {
    aAct = nodeA < n;
    bAct = nodeB < n;
    int pA0 = 0, pA1 = 0, pB0 = 0, pB1 = 0;
    float dcA = 0.f, dcB = 0.f;
    if (aAct) { pA0 = offs[nodeA]; pA1 = offs[nodeA + 1]; dcA = dis[nodeA]; }
    if (bAct) { pB0 = offs[nodeB]; pB1 = offs[nodeB + 1]; dcB = dis[nodeB]; }
    float4 accA = make_float4(0.f, 0.f, 0.f, 0.f);
    float4 accB = make_float4(0.f, 0.f, 0.f, 0.f);
    int baseA = pA0, baseB = pB0;
    while (baseA < pA1 || baseB < pB1) {
        int cntA = pA1 - baseA;
        cntA = cntA > 64 ? 64 : (cntA < 0 ? 0 : cntA);
        int cntB = pB1 - baseB;
        cntB = cntB > 64 ? 64 : (cntB < 0 ? 0 : cntB);
        int2 eA = csr[cntA > 0 ? baseA + (lane < cntA ? lane : cntA - 1) : 0];
        int2 eB = csr[cntB > 0 ? baseB + (lane < cntB ? lane : cntB - 1) : 0];
        int cmax = cntA > cntB ? cntA : cntB;
        for (int j = 0; j < cmax; j += 16) {
            if (j < cntA) {
#pragma unroll
                for (int u = 0; u < 4; ++u) AGG_USTEP(accA, eA, cntA, u);
            }
            if (j < cntB) {
#pragma unroll
                for (int u = 0; u < 4; ++u) AGG_USTEP(accB, eB, cntB, u);
            }
            if (j + 8 < cntA) {
#pragma unroll
                for (int u = 4; u < 8; ++u) AGG_USTEP(accA, eA, cntA, u);
            }
            if (j + 8 < cntB) {
#pragma unroll
                for (int u = 4; u < 8; ++u) AGG_USTEP(accB, eB, cntB, u);
            }
        }
        baseA += 64;
        baseB += 64;
    }
    accA.x += __shfl_xor(accA.x, 32, 64);
    accA.y += __shfl_xor(accA.y, 32, 64);
    accA.z += __shfl_xor(accA.z, 32, 64);
    accA.w += __shfl_xor(accA.w, 32, 64);
    accB.x += __shfl_xor(accB.x, 32, 64);
    accB.y += __shfl_xor(accB.y, 32, 64);
    accB.z += __shfl_xor(accB.z, 32, 64);
    accB.w += __shfl_xor(accB.w, 32, 64);
    xA = make_float4(fmaxf(bs.x + dcA * accA.x, 0.f), fmaxf(bs.y + dcA * accA.y, 0.f),
                     fmaxf(bs.z + dcA * accA.z, 0.f), fmaxf(bs.w + dcA * accA.w, 0.f));
    xB = make_float4(fmaxf(bs.x + dcB * accB.x, 0.f), fmaxf(bs.y + dcB * accB.y, 0.f),
                     fmaxf(bs.z + dcB * accB.z, 0.f), fmaxf(bs.w + dcB * accB.w, 0.f));
}

// ---------------- aggregation: 128-thread blocks (2 waves, 4 nodes/block) -------------
// Round-7 change: block 256->128 threads. Each node is still processed wholly inside one
// wave by the unchanged agg_node_dual (bit-identical per-node sums). Finer workgroup
// granularity -> more resident workgroups + better load balance at degree variance
// (round-3 PMC: OccupancyPercent 43% with VALUBusy 11% and HBM 7% -> TLP-starved).
// Only the STATS partial partition changes (which nodes -> which pS column), proven
// tolerance class in round 4->5 (absmax stayed 2^-9).

template <bool STATS>
__global__ __launch_bounds__(128) void agg_kernel(const uint2* __restrict__ hw2,
                                                  const int2* __restrict__ csr,
                                                  const int* __restrict__ offs,
                                                  const float* __restrict__ dis,
                                                  const float4* __restrict__ bias4,
                                                  unsigned short* __restrict__ xoutb, int n,
                                                  float* __restrict__ pS,
                                                  float* __restrict__ pQ, int NB) {
    int lane = threadIdx.x & 63;
    int wv = threadIdx.x >> 6;  // 0..1
    int half = lane >> 5;
    int fl = lane & 31;
    float4 bs = bias4[fl];
    float4 s = make_float4(0.f, 0.f, 0.f, 0.f), s2 = make_float4(0.f, 0.f, 0.f, 0.f);
    int nGroups = (n + 3) >> 2;  // 4 nodes per group
    for (int grp = blockIdx.x; grp < nGroups; grp += gridDim.x) {
        int nodeA = grp * 4 + wv;
        int nodeB = grp * 4 + 2 + wv;
        float4 xA, xB;
        bool aAct, bAct;
        agg_node_dual(hw2, csr, offs, dis, bs, nodeA, nodeB, n, lane, half, fl, xA, xB,
                      aAct, bAct);
        if (half == 0) {
            if (aAct) {
                ushort4 o = make_ushort4(f2bf(xA.x), f2bf(xA.y), f2bf(xA.z), f2bf(xA.w));
                *(ushort4*)&xoutb[(long)nodeA * D + fl * 4] = o;
                if (STATS) {
                    s.x += xA.x; s.y += xA.y; s.z += xA.z; s.w += xA.w;
                    s2.x += xA.x * xA.x; s2.y += xA.y * xA.y;
                    s2.z += xA.z * xA.z; s2.w += xA.w * xA.w;
                }
            }
            if (bAct) {
                ushort4 o = make_ushort4(f2bf(xB.x), f2bf(xB.y), f2bf(xB.z), f2bf(xB.w));
                *(ushort4*)&xoutb[(long)nodeB * D + fl * 4] = o;
                if (STATS) {
                    s.x += xB.x; s.y += xB.y; s.z += xB.z; s.w += xB.w;
                    s2.x += xB.x * xB.x; s2.y += xB.y * xB.y;
                    s2.z += xB.z * xB.z; s2.w += xB.w * xB.w;
                }
            }
        }
    }
    if (STATS) {
        __shared__ float4 smS[128], smQ[128];
        smS[threadIdx.x] = s;
        smQ[threadIdx.x] = s2;
        __syncthreads();
        if (threadIdx.x < 32) {
            float4 a = smS[threadIdx.x], q = smQ[threadIdx.x];
            float4 b = smS[64 + threadIdx.x], c = smQ[64 + threadIdx.x];
            a.x += b.x; a.y += b.y; a.z += b.z; a.w += b.w;
            q.x += c.x; q.y += c.y; q.z += c.z; q.w += c.w;
            int f0 = 4 * threadIdx.x;
            pS[(f0 + 0) * NB + blockIdx.x] = a.x;
            pS[(f0 + 1) * NB + blockIdx.x] = a.y;
            pS[(f0 + 2) * NB + blockIdx.x] = a.z;
            pS[(f0 + 3) * NB + blockIdx.x] = a.w;
            pQ[(f0 + 0) * NB + blockIdx.x] = q.x;
            pQ[(f0 + 1) * NB + blockIdx.x] = q.y;
            pQ[(f0 + 2) * NB + blockIdx.x] = q.z;
            pQ[(f0 + 3) * NB + blockIdx.x] = q.w;
        }
    }
}

// ---------------- softmax pooling (precomputed m/s/bounds; vectorized 16B reads) ------

__global__ __launch_bounds__(1024) void pool_kernel(const float* __restrict__ tfidf,
                                                    const int* __restrict__ gb,
                                                    const float* __restrict__ gm,
                                                    const float* __restrict__ gs,
                                                    const unsigned short* __restrict__ xb,
                                                    float* __restrict__ out) {
    int g = blockIdx.x;
    int tid = threadIdx.x;
    int s0 = gb[g], s1 = gb[g + 1];
    float m = gm[g], s = gs[g];
    int fb = tid & 15;    // feature block: feats fb*8 .. fb*8+7
    int slot = tid >> 4;  // 0..63 row slot
    float acc[8];
#pragma unroll
    for (int k = 0; k < 8; ++k) acc[k] = 0.f;
    for (int i = s0 + slot; i < s1; i += 64) {
        float wgt = __expf(tfidf[i] - m);
        uint4 raw = *(const uint4*)&xb[(long)i * D + fb * 8];
        acc[0] += wgt * bflo(raw.x);
        acc[1] += wgt * bfhi(raw.x);
        acc[2] += wgt * bflo(raw.y);
        acc[3] += wgt * bfhi(raw.y);
        acc[4] += wgt * bflo(raw.z);
        acc[5] += wgt * bfhi(raw.z);
        acc[6] += wgt * bflo(raw.w);
        acc[7] += wgt * bfhi(raw.w);
    }
    __shared__ float racc[64][132];  // +4 pad -> worst 2-way bank alias (free)
#pragma unroll
    for (int k = 0; k < 8; ++k) racc[slot][fb * 8 + k] = acc[k];
    __syncthreads();
    for (int off = 32; off > 0; off >>= 1) {
        if (slot < off) {
#pragma unroll
            for (int k = 0; k < 8; ++k) racc[slot][fb * 8 + k] += racc[slot + off][fb * 8 + k];
        }
        __syncthreads();
    }
    if (tid < D) out[g * D + tid] = (s1 > s0) ? racc[0][tid] / s : 0.f;
}

// ---------------- launch ----------------

extern "C" void kernel_launch(void* const* d_in, const int* in_sizes, int n_in, void* d_out,
                              int out_size, void* d_ws, size_t ws_size, hipStream_t stream) {
    const int N = in_sizes[0];
    const int E = in_sizes[4];
    const int G = out_size / D;
    const int BN_GRID = 768;
    const int AGG_GRID = 4096;  // 128-thr blocks: 8192 waves resident-capable

    const int* x_index = (const int*)d_in[0];
    const float* tfidf = (const float*)d_in[1];
    const int* ei_row = (const int*)d_in[2];
    const int* ei_col = ei_row + E;
    const int* batch = (const int*)d_in[3];
    const float* edge_attr = (const float*)d_in[4];
    const float* emb = (const float*)d_in[5];
    const float* gamma1 = (const float*)d_in[6];
    const float* beta1 = (const float*)d_in[7];
    const float* W1 = (const float*)d_in[8];
    const float* b1 = (const float*)d_in[9];
    const float* gamma2 = (const float*)d_in[10];
    const float* beta2 = (const float*)d_in[11];
    const float* W2 = (const float*)d_in[12];
    const float* b2 = (const float*)d_in[13];
    float* out = (float*)d_out;

    // ---- workspace carve (256B aligned) ----
    size_t off = 0;
    char* base = (char*)d_ws;
    auto carve = [&](size_t bytes) -> void* {
        void* p = base + off;
        off = (off + bytes + 255) & ~(size_t)255;
        return p;
    };
    unsigned short* bufA = (unsigned short*)carve((size_t)N * D * 2);  // h' (bf16)
    unsigned short* bufB = (unsigned short*)carve((size_t)N * D * 2);  // x (bf16)
    long long* pk = (long long*)carve((size_t)E * 8);                  // packed (row, ea)
    int2* csr = (int2*)carve((size_t)E * 8);                           // (row, ea)
    int* rank = (int*)carve((size_t)E * 4);                            // arrival rank
    int* cnt = (int*)carve((size_t)N * 4);                             // zeroed in prep_w
    float* dis = (float*)carve((size_t)N * 4);
    int* offs = (int*)carve((size_t)(N + 1) * 4);
    float* scale1 = (float*)carve(D * 4);
    float* shift1 = (float*)carve(D * 4);
    float* scale2 = (float*)carve(D * 4);
    float* shift2 = (float*)carve(D * 4);
    unsigned short* WT1b = (unsigned short*)carve((size_t)D * D * 2);
    unsigned short* WT2b = (unsigned short*)carve((size_t)D * D * 2);
    float* pS = (float*)carve((size_t)AGG_GRID * D * 4);
    float* pQ = (float*)carve((size_t)AGG_GRID * D * 4);
    float* gm = (float*)carve((size_t)G * 4);
    float* gs = (float*)carve((size_t)G * 4);
    int* gb = (int*)carve((size_t)(G + 1) * 4);
    (void)ws_size;
    (void)n_in;

    // ---- W -> bf16 transposed + cnt zeroing ----
    prep_w<<<2 * D, D, 0, stream>>>(W1, W2, WT1b, WT2b, cnt, N);

    // ---- hist (atomic) + layer-1 BN stats (gather) + per-graph softmax stats ----
    int HB = cdiv(E, 256);
    hist_bn_kernel<<<HB + BN_GRID + G, 256, 0, stream>>>(ei_col, cnt, rank, E, emb, x_index,
                                                         pS, pQ, N, HB, BN_GRID, tfidf,
                                                         batch, gm, gs, gb, G);
    // ---- scan (offs) overlapped with layer-1 BN reduce (pS/pQ complete) ----
    int nb = cdiv(N, 1024);
    scan_bnred_kernel<<<nb + D, 1024, 0, stream>>>(cnt, offs, N, E, nb, pS, pQ, BN_GRID,
                                                   gamma1, beta1, scale1, shift1, (float)N);
    scatter_pack<<<cdiv(E, 256), 256, 0, stream>>>(ei_row, ei_col, edge_attr, rank, offs, pk,
                                                   E);
    sort_deg_kernel<<<cdiv(N, 16), 256, 0, stream>>>(pk, offs, dis, csr, N);

    // ---- layer 1 ----
    gemm_mfma<true, false><<<cdiv(N, 64), 256, 0, stream>>>(emb, x_index, scale1, shift1, WT1b,
                                                            dis, bufA, N);
    agg_kernel<true><<<AGG_GRID, 128, 0, stream>>>((const uint2*)bufA, csr, offs, dis,
                                                   (const float4*)b1, bufB, N, pS, pQ,
                                                   AGG_GRID);

    // ---- layer 2 ----
    bn_reduce<<<D, 256, 0, stream>>>(pS, pQ, AGG_GRID, gamma2, beta2, scale2, shift2, (float)N);
    gemm_mfma<false, true><<<cdiv(N, 64), 256, 0, stream>>>(bufB, nullptr, scale2, shift2,
                                                            WT2b, dis, bufA, N);
    agg_kernel<false><<<cdiv(N, 4), 128, 0, stream>>>((const uint2*)bufA, csr, offs, dis,
                                                      (const float4*)b2, bufB, N, nullptr,
                                                      nullptr, 0);

    // ---- softmax pooling (bf16 x, precomputed stats) ----
    pool_kernel<<<G, 1024, 0, stream>>>(tfidf, gb, gm, gs, bufB, out);
}

// Round 8
// 255.647 us; speedup vs baseline: 1.0335x; 1.0335x over previous
//
#include <hip/hip_runtime.h>
#include <hip/hip_bf16.h>

#define D 128
#define EPSV 1e-5f

static inline int cdiv(int a, int b) { return (a + b - 1) / b; }

typedef __attribute__((ext_vector_type(8))) short short8v;
typedef __attribute__((ext_vector_type(4))) float floatx4;

// bf16 RNE pack / unpack helpers
__device__ __forceinline__ unsigned short f2bf(float f) {
    unsigned int x = __float_as_uint(f);
    unsigned int r = x + 0x7fffu + ((x >> 16) & 1u);
    return (unsigned short)(r >> 16);
}
__device__ __forceinline__ float bflo(unsigned int u) { return __uint_as_float(u << 16); }
__device__ __forceinline__ float bfhi(unsigned int u) {
    return __uint_as_float(u & 0xffff0000u);
}

// ---------------- W -> bf16 transposed + cnt zeroing (once per launch) ----------------

__global__ void prep_w(const float* __restrict__ W1, const float* __restrict__ W2,
                       unsigned short* __restrict__ WT1, unsigned short* __restrict__ WT2,
                       int* __restrict__ cnt, int N) {
    int b = blockIdx.x;
    const float* W = (b < D) ? W1 : W2;
    unsigned short* WT = (b < D) ? WT1 : WT2;
    int k = b & (D - 1);
    int n = threadIdx.x;
    WT[n * D + k] = f2bf(W[k * D + n]);
    int gid = b * D + n;
    for (int i = gid; i < N; i += 2 * D * D) cnt[i] = 0;
}

// ---------------- hist + layer-1 BN stats + per-graph softmax stats -------------------
// blocks [0,HB): edge histogram + arrival rank (atomic-bound, low BW).
// blocks [HB,HB+NB): emb-gather BN partials (memory-bound) — exact bn_stats numerics.
// blocks [HB+NB,HB+NB+G): per-graph softmax m/s + bounds (depends only on tfidf/batch).
// m is exact (max order-insensitive); s reorder only enters pool's FINAL division.

__global__ __launch_bounds__(256) void hist_bn_kernel(
    const int* __restrict__ col, int* __restrict__ cnt, int* __restrict__ rank, int E_,
    const float* __restrict__ emb, const int* __restrict__ idx,
    float* __restrict__ pS, float* __restrict__ pQ, int n, int HB, int NB,
    const float* __restrict__ tfidf, const int* __restrict__ batch,
    float* __restrict__ gm, float* __restrict__ gs, int* __restrict__ gb, int G_) {
    int tid = threadIdx.x;
    if ((int)blockIdx.x < HB) {
        int e = blockIdx.x * 256 + tid;
        if (e < E_) rank[e] = atomicAdd(&cnt[col[e]], 1);
        return;
    }
    int bid = blockIdx.x - HB;
    if (bid >= NB) {
        // ---- per-graph softmax stats ----
        int g = bid - NB;
        __shared__ int sb2[2];
        if (tid < 2) {
            int target = g + tid;
            int lo = 0, hi = n;
            while (lo < hi) {
                int mid = (lo + hi) >> 1;
                if (batch[mid] < target) lo = mid + 1;
                else hi = mid;
            }
            sb2[tid] = lo;
        }
        __syncthreads();
        int s0 = sb2[0], s1 = sb2[1];
        __shared__ float red[256];
        float m = -1e30f;
        for (int i = s0 + tid; i < s1; i += 256) m = fmaxf(m, tfidf[i]);
        red[tid] = m;
        __syncthreads();
        for (int off = 128; off > 0; off >>= 1) {
            if (tid < off) red[tid] = fmaxf(red[tid], red[tid + off]);
            __syncthreads();
        }
        m = red[0];
        __syncthreads();
        float s = 0.f;
        for (int i = s0 + tid; i < s1; i += 256) s += __expf(tfidf[i] - m);
        red[tid] = s;
        __syncthreads();
        for (int off = 128; off > 0; off >>= 1) {
            if (tid < off) red[tid] += red[tid + off];
            __syncthreads();
        }
        if (tid == 0) {
            gm[g] = m;
            gs[g] = red[0];
            gb[g] = s0;
            if (g == G_ - 1) gb[G_] = s1;
        }
        return;
    }
    // ---- bn-stats path (layer 1: emb gather; exact bn_stats numerics) ----
    int sub = tid >> 5;
    int q = tid & 31;
    float4 s = make_float4(0, 0, 0, 0), s2 = make_float4(0, 0, 0, 0);
    int stride = NB * 8;
    int i = bid * 8 + sub;
    int r_next = (i < n) ? idx[i] : 0;
    for (; i < n; i += stride) {
        int r = r_next;
        int i2 = i + stride;
        if (i2 < n) r_next = idx[i2];
        float4 v = *(const float4*)&emb[(long)r * D + q * 4];
        s.x += v.x; s.y += v.y; s.z += v.z; s.w += v.w;
        s2.x += v.x * v.x; s2.y += v.y * v.y; s2.z += v.z * v.z; s2.w += v.w * v.w;
    }
    __shared__ float4 redA[256], redB[256];
    redA[tid] = s;
    redB[tid] = s2;
    __syncthreads();
    for (int off = 128; off >= 32; off >>= 1) {
        if (tid < off) {
            float4 a = redA[tid + off], b = redB[tid + off];
            redA[tid].x += a.x; redA[tid].y += a.y;
            redA[tid].z += a.z; redA[tid].w += a.w;
            redB[tid].x += b.x; redB[tid].y += b.y;
            redB[tid].z += b.z; redB[tid].w += b.w;
        }
        __syncthreads();
    }
    if (tid < 32) {
        float4 a = redA[tid], b = redB[tid];
        int bofs = bid;
        pS[(q * 4 + 0) * NB + bofs] = a.x;
        pS[(q * 4 + 1) * NB + bofs] = a.y;
        pS[(q * 4 + 2) * NB + bofs] = a.z;
        pS[(q * 4 + 3) * NB + bofs] = a.w;
        pQ[(q * 4 + 0) * NB + bofs] = b.x;
        pQ[(q * 4 + 1) * NB + bofs] = b.y;
        pQ[(q * 4 + 2) * NB + bofs] = b.z;
        pQ[(q * 4 + 3) * NB + bofs] = b.w;
    }
}

// ---------------- scan + layer-1 BN reduce (one dispatch) ----------------

__global__ void scan_bnred_kernel(const int* __restrict__ cnt, int* __restrict__ offs,
                                  int n, int E_, int nbk,
                                  const float* __restrict__ pS, const float* __restrict__ pQ,
                                  int nb2, const float* __restrict__ gamma,
                                  const float* __restrict__ beta, float* __restrict__ scale,
                                  float* __restrict__ shift, float nn) {
    int tid = threadIdx.x;
    if ((int)blockIdx.x >= nbk) {
        int d = blockIdx.x - nbk;
        __shared__ float smS[256], smQ[256];
        if (tid < 256) {
            float s = 0.f, q = 0.f;
            for (int b = tid; b < nb2; b += 256) {
                s += pS[d * nb2 + b];
                q += pQ[d * nb2 + b];
            }
            smS[tid] = s;
            smQ[tid] = q;
        }
        __syncthreads();
        for (int off = 128; off > 0; off >>= 1) {
            if (tid < off) {
                smS[tid] += smS[tid + off];
                smQ[tid] += smQ[tid + off];
            }
            __syncthreads();
        }
        if (tid == 0) {
            float mean = smS[0] / nn;
            float var = smQ[0] / nn - mean * mean;
            float rstd = rsqrtf(var + EPSV);
            float sc = gamma[d] * rstd;
            scale[d] = sc;
            shift[d] = beta[d] - mean * sc;
        }
        return;
    }
    __shared__ int sm[1024];
    __shared__ int sbo_s;
    int lim = blockIdx.x * 1024;
    int pre = 0;
    for (int i = tid; i < lim; i += 1024) pre += cnt[i];
    sm[tid] = pre;
    __syncthreads();
    for (int off = 512; off > 0; off >>= 1) {
        if (tid < off) sm[tid] += sm[tid + off];
        __syncthreads();
    }
    if (tid == 0) {
        sbo_s = sm[0];
        if (blockIdx.x == 0) offs[n] = E_;
    }
    __syncthreads();
    int i = lim + tid;
    int v = (i < n) ? cnt[i] : 0;
    sm[tid] = v;
    __syncthreads();
    for (int off = 1; off < 1024; off <<= 1) {
        int t = (tid >= off) ? sm[tid - off] : 0;
        __syncthreads();
        sm[tid] += t;
        __syncthreads();
    }
    if (i < n) offs[i] = sm[tid] - v + sbo_s;
}

// scatter packed (src_row<<32 | ea_bits) into CSR slot offs[col]+rank.
__global__ void scatter_pack(const int* __restrict__ row, const int* __restrict__ col,
                             const float* __restrict__ ea, const int* __restrict__ rank,
                             const int* __restrict__ offs, long long* __restrict__ pk,
                             int E_) {
    int e = blockIdx.x * blockDim.x + threadIdx.x;
    if (e >= E_) return;
    int p = offs[col[e]] + rank[e];
    pk[p] = ((long long)row[e] << 32) | (unsigned int)__float_as_int(ea[e]);
}

// ---------------- degree-adaptive sort (round-6 PASS) ----------------
// NUMERICS: bit-identical to the 64-wide baseline (see round-6 analysis).

__global__ __launch_bounds__(256) void sort_deg_kernel(const long long* __restrict__ pk,
                                                       const int* __restrict__ offs,
                                                       float* __restrict__ dis,
                                                       int2* __restrict__ csr, int n) {
    int w = blockIdx.x * 4 + (threadIdx.x >> 6);
    int lane = threadIdx.x & 63;
    int n0 = w * 4;
    if (n0 >= n) return;
    int g = lane >> 4;
    int node_q = n0 + g;
    int p0q = 0, degq = 0;
    if (node_q < n) {
        p0q = offs[node_q];
        degq = offs[node_q + 1] - p0q;
    }
    int dmax = degq;
    dmax = max(dmax, __shfl_xor(dmax, 16, 64));
    dmax = max(dmax, __shfl_xor(dmax, 32, 64));
    if (dmax <= 16) {
        int sub = lane & 15;
        long long v = (sub < degq) ? pk[p0q + sub] : 0x7fffffffffffffffLL;
        for (int k = 2; k <= 16; k <<= 1) {
            for (int j = k >> 1; j > 0; j >>= 1) {
                long long partner = __shfl_xor(v, j, 64);
                bool up = ((sub & k) == 0);
                bool keepMin = ((sub & j) == 0);
                long long mn = v < partner ? v : partner;
                long long mx = v < partner ? partner : v;
                v = (up == keepMin) ? mn : mx;
            }
        }
        int r = (int)(v >> 32);
        int eab = (int)(v & 0xffffffffLL);
        if (sub < degq) csr[p0q + sub] = make_int2(r, eab);
        float av = (sub < degq) ? __int_as_float(eab) : 0.f;
        float s = av;
        for (int off = 8; off > 0; off >>= 1) s += __shfl_xor(s, off, 64);
        if (sub == 0 && node_q < n) dis[node_q] = s > 0.f ? rsqrtf(fmaxf(s, EPSV)) : 0.f;
        return;
    }
    int h = lane >> 5;
    int sub5 = lane & 31;
    for (int pass = 0; pass < 2; ++pass) {
        int node_d = n0 + pass * 2 + h;
        int p0d = 0, degd = 0;
        if (node_d < n) {
            p0d = offs[node_d];
            degd = offs[node_d + 1] - p0d;
        }
        int pmax = max(degd, __shfl_xor(degd, 32, 64));
        if (pmax <= 32) {
            long long v = (sub5 < degd) ? pk[p0d + sub5] : 0x7fffffffffffffffLL;
            for (int k = 2; k <= 32; k <<= 1) {
                for (int j = k >> 1; j > 0; j >>= 1) {
                    long long partner = __shfl_xor(v, j, 64);
                    bool up = ((sub5 & k) == 0);
                    bool keepMin = ((sub5 & j) == 0);
                    long long mn = v < partner ? v : partner;
                    long long mx = v < partner ? partner : v;
                    v = (up == keepMin) ? mn : mx;
                }
            }
            int r = (int)(v >> 32);
            int eab = (int)(v & 0xffffffffLL);
            if (sub5 < degd) csr[p0d + sub5] = make_int2(r, eab);
            float av = (sub5 < degd) ? __int_as_float(eab) : 0.f;
            float s = av;
            for (int off = 16; off > 0; off >>= 1) s += __shfl_xor(s, off, 64);
            if (sub5 == 0 && node_d < n) dis[node_d] = s > 0.f ? rsqrtf(fmaxf(s, EPSV)) : 0.f;
        } else {
            for (int qq = 0; qq < 2; ++qq) {
                int node = n0 + pass * 2 + qq;
                if (node >= n) continue;
                int p0 = offs[node], p1 = offs[node + 1];
                int deg = p1 - p0;
                if (deg <= 64) {
                    long long v = (lane < deg) ? pk[p0 + lane] : 0x7fffffffffffffffLL;
                    for (int k = 2; k <= 64; k <<= 1) {
                        for (int j = k >> 1; j > 0; j >>= 1) {
                            long long partner = __shfl_xor(v, j, 64);
                            bool up = ((lane & k) == 0);
                            bool keepMin = ((lane & j) == 0);
                            long long mn = v < partner ? v : partner;
                            long long mx = v < partner ? partner : v;
                            v = (up == keepMin) ? mn : mx;
                        }
                    }
                    int r = (int)(v >> 32);
                    int eab = (int)(v & 0xffffffffLL);
                    if (lane < deg) csr[p0 + lane] = make_int2(r, eab);
                    float av = (lane < deg) ? __int_as_float(eab) : 0.f;
                    float s = av;
                    for (int off = 32; off > 0; off >>= 1) s += __shfl_xor(s, off, 64);
                    if (lane == 0) dis[node] = s > 0.f ? rsqrtf(fmaxf(s, EPSV)) : 0.f;
                } else {
                    if (lane == 0) {  // deterministic O(d^2) selection fallback
                        float dg = 0.f;
                        for (int p = p0; p < p1; ++p) {
                            long long best = 0x7fffffffffffffffLL;
                            for (int q2 = p0; q2 < p1; ++q2) {
                                long long cand = pk[q2];
                                int less = 0;
                                for (int q3 = p0; q3 < p1; ++q3)
                                    if (pk[q3] < cand) ++less;
                                if (less == p - p0) { best = cand; break; }
                            }
                            int r = (int)(best >> 32);
                            int eab = (int)(best & 0xffffffffLL);
                            csr[p] = make_int2(r, eab);
                            dg += __int_as_float(eab);
                        }
                        dis[node] = dg > 0.f ? rsqrtf(fmaxf(dg, EPSV)) : 0.f;
                    }
                }
            }
        }
    }
}

__global__ __launch_bounds__(256) void bn_reduce(const float* __restrict__ pS,
                                                 const float* __restrict__ pQ, int nb,
                                                 const float* __restrict__ gamma,
                                                 const float* __restrict__ beta,
                                                 float* __restrict__ scale,
                                                 float* __restrict__ shift, float n) {
    int d = blockIdx.x;
    int tid = threadIdx.x;
    float s = 0.f, q = 0.f;
    for (int b = tid; b < nb; b += 256) {
        s += pS[d * nb + b];
        q += pQ[d * nb + b];
    }
    __shared__ float smS[256], smQ[256];
    smS[tid] = s;
    smQ[tid] = q;
    __syncthreads();
    for (int off = 128; off > 0; off >>= 1) {
        if (tid < off) {
            smS[tid] += smS[tid + off];
            smQ[tid] += smQ[tid + off];
        }
        __syncthreads();
    }
    if (tid == 0) {
        float mean = smS[0] / n;
        float var = smQ[0] / n - mean * mean;
        float rstd = rsqrtf(var + EPSV);
        float sc = gamma[d] * rstd;
        scale[d] = sc;
        shift[d] = beta[d] - mean * sc;
    }
}

// ---------------- MFMA GEMM: h' = dis[r] * (bn(src) @ W), out bf16 ----------

template <bool GATHER, bool BF16IN>
__global__ __launch_bounds__(256) void gemm_mfma(const void* __restrict__ srcv,
                                                 const int* __restrict__ idx,
                                                 const float* __restrict__ scale,
                                                 const float* __restrict__ shift,
                                                 const unsigned short* __restrict__ WTb,
                                                 const float* __restrict__ disv,
                                                 unsigned short* __restrict__ outb, int n) {
    __shared__ unsigned short xsb[64 * 136];   // 17.0 KB
    __shared__ unsigned short wsb[128 * 136];  // 34.0 KB (reused as float scratch in epi)
    int tid = threadIdx.x;
    int r0 = blockIdx.x * 64;
    const float4* scale4 = (const float4*)scale;
    const float4* shift4 = (const float4*)shift;
    for (int it = 0; it < 4; ++it) {
        int flat = it * 256 + tid;  // 0..1023
        int r = flat >> 4;
        int c16 = flat & 15;
        int gr = r0 + r;
        float4 v0 = make_float4(0, 0, 0, 0), v1 = make_float4(0, 0, 0, 0);
        if (gr < n) {
            int srow = GATHER ? idx[gr] : gr;
            float4 x0, x1;
            if (BF16IN) {
                const unsigned short* sb = (const unsigned short*)srcv;
                uint4 raw = *(const uint4*)&sb[(long)srow * D + c16 * 8];
                x0 = make_float4(bflo(raw.x), bfhi(raw.x), bflo(raw.y), bfhi(raw.y));
                x1 = make_float4(bflo(raw.z), bfhi(raw.z), bflo(raw.w), bfhi(raw.w));
            } else {
                const float* sf = (const float*)srcv;
                x0 = *(const float4*)&sf[(long)srow * D + c16 * 8];
                x1 = *(const float4*)&sf[(long)srow * D + c16 * 8 + 4];
            }
            float4 sa = scale4[c16 * 2], sb2 = shift4[c16 * 2];
            float4 sc = scale4[c16 * 2 + 1], sd = shift4[c16 * 2 + 1];
            v0 = make_float4(x0.x * sa.x + sb2.x, x0.y * sa.y + sb2.y, x0.z * sa.z + sb2.z,
                             x0.w * sa.w + sb2.w);
            v1 = make_float4(x1.x * sc.x + sd.x, x1.y * sc.y + sd.y, x1.z * sc.z + sd.z,
                             x1.w * sc.w + sd.w);
        }
        int phys = c16 ^ (r & 15);
        ushort4 o0 = make_ushort4(f2bf(v0.x), f2bf(v0.y), f2bf(v0.z), f2bf(v0.w));
        ushort4 o1 = make_ushort4(f2bf(v1.x), f2bf(v1.y), f2bf(v1.z), f2bf(v1.w));
        *(ushort4*)&xsb[r * 136 + phys * 8] = o0;
        *(ushort4*)&xsb[r * 136 + phys * 8 + 4] = o1;
    }
    for (int it = 0; it < 8; ++it) {
        int flat = it * 256 + tid;  // 0..2047
        int nrow = flat >> 4;
        int c16 = flat & 15;
        int phys = c16 ^ (nrow & 15);
        uint4 w = *(const uint4*)&WTb[nrow * D + c16 * 8];
        *(uint4*)&wsb[nrow * 136 + phys * 8] = w;
    }
    __syncthreads();
    int wv = tid >> 6;
    int lane = tid & 63;
    int m = lane & 15, q = lane >> 4;
    int r0w = wv * 16;
    floatx4 acc[8];
#pragma unroll
    for (int t = 0; t < 8; ++t) acc[t] = (floatx4)(0.f);
#pragma unroll
    for (int ks = 0; ks < 4; ++ks) {
        int c16 = ks * 4 + q;
        short8v a = *(short8v*)&xsb[(r0w + m) * 136 + (c16 ^ ((r0w + m) & 15)) * 8];
#pragma unroll
        for (int t = 0; t < 8; ++t) {
            short8v b = *(short8v*)&wsb[(t * 16 + m) * 136 + (c16 ^ m) * 8];
            acc[t] = __builtin_amdgcn_mfma_f32_16x16x32_bf16(a, b, acc[t], 0, 0, 0);
        }
    }
    __syncthreads();
    float* fl = (float*)wsb;  // 64 x 132 floats
#pragma unroll
    for (int t = 0; t < 8; ++t) {
#pragma unroll
        for (int r = 0; r < 4; ++r) {
            fl[(r0w + q * 4 + r) * 132 + t * 16 + m] = acc[t][r];
        }
    }
    __syncthreads();
    for (int it = 0; it < 4; ++it) {
        int c = it * 256 + tid;
        int r = c >> 4;
        int k8 = (c & 15) * 8;
        int gr = r0 + r;
        if (gr < n) {
            float dsc = disv[gr];  // fold dis[row] into h' (removes fill_w)
            float4 v0 = *(float4*)&fl[r * 132 + k8];
            float4 v1 = *(float4*)&fl[r * 132 + k8 + 4];
            ushort4 o0 = make_ushort4(f2bf(v0.x * dsc), f2bf(v0.y * dsc), f2bf(v0.z * dsc),
                                      f2bf(v0.w * dsc));
            ushort4 o1 = make_ushort4(f2bf(v1.x * dsc), f2bf(v1.y * dsc), f2bf(v1.z * dsc),
                                      f2bf(v1.w * dsc));
            *(ushort4*)&outb[(long)gr * D + k8] = o0;
            *(ushort4*)&outb[(long)gr * D + k8 + 4] = o1;
        }
    }
}

// ---------------- dual-node aggregation body (round-4/5/6 PASS) ----------
// NUMERICS: per node, even/odd-half partition + ascending edge order per half are
// bit-identical to the verified baseline (absmax 2^-9). Do NOT change the partition.
// Round-7 lesson: 128-thread blocks regress (−7 us); 256-thread blocks are optimal.

#define AGG_USTEP(acc_, e_, cnt_, UU)                                   \
    {                                                                   \
        int jj = j + 2 * (UU) + half;                                   \
        bool ok = jj < (cnt_);                                          \
        int sel = ok ? jj : 0;                                          \
        int r = __shfl((e_).x, sel, 64);                                \
        float w = ok ? __int_as_float(__shfl((e_).y, sel, 64)) : 0.f;   \
        uint2 uu = hw2[(long)r * 32 + fl];                              \
        (acc_).x += w * bflo(uu.x);                                     \
        (acc_).y += w * bfhi(uu.x);                                     \
        (acc_).z += w * bflo(uu.y);                                     \
        (acc_).w += w * bfhi(uu.y);                                     \
    }

__device__ __forceinline__ void agg_node_dual(const uint2* __restrict__ hw2,
                                              const int2* __restrict__ csr,
                                              const int* __restrict__ offs,
                                              const float* __restrict__ dis, float4 bs,
                                              int nodeA, int nodeB, int n, int lane,
                                              int half, int fl, float4& xA, float4& xB,
                                              bool& aAct, bool& bAct) {
    aAct = nodeA < n;
    bAct = nodeB < n;
    int pA0 = 0, pA1 = 0, pB0 = 0, pB1 = 0;
    float dcA = 0.f, dcB = 0.f;
    if (aAct) { pA0 = offs[nodeA]; pA1 = offs[nodeA + 1]; dcA = dis[nodeA]; }
    if (bAct) { pB0 = offs[nodeB]; pB1 = offs[nodeB + 1]; dcB = dis[nodeB]; }
    float4 accA = make_float4(0.f, 0.f, 0.f, 0.f);
    float4 accB = make_float4(0.f, 0.f, 0.f, 0.f);
    int baseA = pA0, baseB = pB0;
    while (baseA < pA1 || baseB < pB1) {
        int cntA = pA1 - baseA;
        cntA = cntA > 64 ? 64 : (cntA < 0 ? 0 : cntA);
        int cntB = pB1 - baseB;
        cntB = cntB > 64 ? 64 : (cntB < 0 ? 0 : cntB);
        int2 eA = csr[cntA > 0 ? baseA + (lane < cntA ? lane : cntA - 1) : 0];
        int2 eB = csr[cntB > 0 ? baseB + (lane < cntB ? lane : cntB - 1) : 0];
        int cmax = cntA > cntB ? cntA : cntB;
        for (int j = 0; j < cmax; j += 16) {
            if (j < cntA) {
#pragma unroll
                for (int u = 0; u < 4; ++u) AGG_USTEP(accA, eA, cntA, u);
            }
            if (j < cntB) {
#pragma unroll
                for (int u = 0; u < 4; ++u) AGG_USTEP(accB, eB, cntB, u);
            }
            if (j + 8 < cntA) {
#pragma unroll
                for (int u = 4; u < 8; ++u) AGG_USTEP(accA, eA, cntA, u);
            }
            if (j + 8 < cntB) {
#pragma unroll
                for (int u = 4; u < 8; ++u) AGG_USTEP(accB, eB, cntB, u);
            }
        }
        baseA += 64;
        baseB += 64;
    }
    accA.x += __shfl_xor(accA.x, 32, 64);
    accA.y += __shfl_xor(accA.y, 32, 64);
    accA.z += __shfl_xor(accA.z, 32, 64);
    accA.w += __shfl_xor(accA.w, 32, 64);
    accB.x += __shfl_xor(accB.x, 32, 64);
    accB.y += __shfl_xor(accB.y, 32, 64);
    accB.z += __shfl_xor(accB.z, 32, 64);
    accB.w += __shfl_xor(accB.w, 32, 64);
    xA = make_float4(fmaxf(bs.x + dcA * accA.x, 0.f), fmaxf(bs.y + dcA * accA.y, 0.f),
                     fmaxf(bs.z + dcA * accA.z, 0.f), fmaxf(bs.w + dcA * accA.w, 0.f));
    xB = make_float4(fmaxf(bs.x + dcB * accB.x, 0.f), fmaxf(bs.y + dcB * accB.y, 0.f),
                     fmaxf(bs.z + dcB * accB.z, 0.f), fmaxf(bs.w + dcB * accB.w, 0.f));
}

template <bool STATS>
__global__ __launch_bounds__(256) void agg_kernel(const uint2* __restrict__ hw2,
                                                  const int2* __restrict__ csr,
                                                  const int* __restrict__ offs,
                                                  const float* __restrict__ dis,
                                                  const float4* __restrict__ bias4,
                                                  unsigned short* __restrict__ xoutb, int n,
                                                  float* __restrict__ pS,
                                                  float* __restrict__ pQ, int NB) {
    int lane = threadIdx.x & 63;
    int wv = threadIdx.x >> 6;
    int half = lane >> 5;
    int fl = lane & 31;
    float4 bs = bias4[fl];
    float4 s = make_float4(0.f, 0.f, 0.f, 0.f), s2 = make_float4(0.f, 0.f, 0.f, 0.f);
    int nGroups = (n + 7) >> 3;
    for (int grp = blockIdx.x; grp < nGroups; grp += gridDim.x) {
        int nodeA = grp * 8 + wv;
        int nodeB = grp * 8 + 4 + wv;
        float4 xA, xB;
        bool aAct, bAct;
        agg_node_dual(hw2, csr, offs, dis, bs, nodeA, nodeB, n, lane, half, fl, xA, xB,
                      aAct, bAct);
        if (half == 0) {
            if (aAct) {
                ushort4 o = make_ushort4(f2bf(xA.x), f2bf(xA.y), f2bf(xA.z), f2bf(xA.w));
                *(ushort4*)&xoutb[(long)nodeA * D + fl * 4] = o;
                if (STATS) {
                    s.x += xA.x; s.y += xA.y; s.z += xA.z; s.w += xA.w;
                    s2.x += xA.x * xA.x; s2.y += xA.y * xA.y;
                    s2.z += xA.z * xA.z; s2.w += xA.w * xA.w;
                }
            }
            if (bAct) {
                ushort4 o = make_ushort4(f2bf(xB.x), f2bf(xB.y), f2bf(xB.z), f2bf(xB.w));
                *(ushort4*)&xoutb[(long)nodeB * D + fl * 4] = o;
                if (STATS) {
                    s.x += xB.x; s.y += xB.y; s.z += xB.z; s.w += xB.w;
                    s2.x += xB.x * xB.x; s2.y += xB.y * xB.y;
                    s2.z += xB.z * xB.z; s2.w += xB.w * xB.w;
                }
            }
        }
    }
    if (STATS) {
        __shared__ float4 smS[256], smQ[256];
        smS[threadIdx.x] = s;
        smQ[threadIdx.x] = s2;
        __syncthreads();
        if (threadIdx.x < 32) {
            float4 a = smS[threadIdx.x], q = smQ[threadIdx.x];
#pragma unroll
            for (int w2 = 1; w2 < 4; ++w2) {
                float4 b = smS[w2 * 64 + threadIdx.x], c = smQ[w2 * 64 + threadIdx.x];
                a.x += b.x; a.y += b.y; a.z += b.z; a.w += b.w;
                q.x += c.x; q.y += c.y; q.z += c.z; q.w += c.w;
            }
            int f0 = 4 * threadIdx.x;
            pS[(f0 + 0) * NB + blockIdx.x] = a.x;
            pS[(f0 + 1) * NB + blockIdx.x] = a.y;
            pS[(f0 + 2) * NB + blockIdx.x] = a.z;
            pS[(f0 + 3) * NB + blockIdx.x] = a.w;
            pQ[(f0 + 0) * NB + blockIdx.x] = q.x;
            pQ[(f0 + 1) * NB + blockIdx.x] = q.y;
            pQ[(f0 + 2) * NB + blockIdx.x] = q.z;
            pQ[(f0 + 3) * NB + blockIdx.x] = q.w;
        }
    }
}

// ---------------- softmax pooling (precomputed m/s/bounds; vectorized 16B reads) ------

__global__ __launch_bounds__(1024) void pool_kernel(const float* __restrict__ tfidf,
                                                    const int* __restrict__ gb,
                                                    const float* __restrict__ gm,
                                                    const float* __restrict__ gs,
                                                    const unsigned short* __restrict__ xb,
                                                    float* __restrict__ out) {
    int g = blockIdx.x;
    int tid = threadIdx.x;
    int s0 = gb[g], s1 = gb[g + 1];
    float m = gm[g], s = gs[g];
    int fb = tid & 15;    // feature block: feats fb*8 .. fb*8+7
    int slot = tid >> 4;  // 0..63 row slot
    float acc[8];
#pragma unroll
    for (int k = 0; k < 8; ++k) acc[k] = 0.f;
    for (int i = s0 + slot; i < s1; i += 64) {
        float wgt = __expf(tfidf[i] - m);
        uint4 raw = *(const uint4*)&xb[(long)i * D + fb * 8];
        acc[0] += wgt * bflo(raw.x);
        acc[1] += wgt * bfhi(raw.x);
        acc[2] += wgt * bflo(raw.y);
        acc[3] += wgt * bfhi(raw.y);
        acc[4] += wgt * bflo(raw.z);
        acc[5] += wgt * bfhi(raw.z);
        acc[6] += wgt * bflo(raw.w);
        acc[7] += wgt * bfhi(raw.w);
    }
    __shared__ float racc[64][132];  // +4 pad -> worst 2-way bank alias (free)
#pragma unroll
    for (int k = 0; k < 8; ++k) racc[slot][fb * 8 + k] = acc[k];
    __syncthreads();
    for (int off = 32; off > 0; off >>= 1) {
        if (slot < off) {
#pragma unroll
            for (int k = 0; k < 8; ++k) racc[slot][fb * 8 + k] += racc[slot + off][fb * 8 + k];
        }
        __syncthreads();
    }
    if (tid < D) out[g * D + tid] = (s1 > s0) ? racc[0][tid] / s : 0.f;
}

// ---------------- launch ----------------

extern "C" void kernel_launch(void* const* d_in, const int* in_sizes, int n_in, void* d_out,
                              int out_size, void* d_ws, size_t ws_size, hipStream_t stream) {
    const int N = in_sizes[0];
    const int E = in_sizes[4];
    const int G = out_size / D;
    const int BN_GRID = 768;
    const int AGG_GRID = 2048;

    const int* x_index = (const int*)d_in[0];
    const float* tfidf = (const float*)d_in[1];
    const int* ei_row = (const int*)d_in[2];
    const int* ei_col = ei_row + E;
    const int* batch = (const int*)d_in[3];
    const float* edge_attr = (const float*)d_in[4];
    const float* emb = (const float*)d_in[5];
    const float* gamma1 = (const float*)d_in[6];
    const float* beta1 = (const float*)d_in[7];
    const float* W1 = (const float*)d_in[8];
    const float* b1 = (const float*)d_in[9];
    const float* gamma2 = (const float*)d_in[10];
    const float* beta2 = (const float*)d_in[11];
    const float* W2 = (const float*)d_in[12];
    const float* b2 = (const float*)d_in[13];
    float* out = (float*)d_out;

    // ---- workspace carve (256B aligned) ----
    size_t off = 0;
    char* base = (char*)d_ws;
    auto carve = [&](size_t bytes) -> void* {
        void* p = base + off;
        off = (off + bytes + 255) & ~(size_t)255;
        return p;
    };
    unsigned short* bufA = (unsigned short*)carve((size_t)N * D * 2);  // h' (bf16)
    unsigned short* bufB = (unsigned short*)carve((size_t)N * D * 2);  // x (bf16)
    long long* pk = (long long*)carve((size_t)E * 8);                  // packed (row, ea)
    int2* csr = (int2*)carve((size_t)E * 8);                           // (row, ea)
    int* rank = (int*)carve((size_t)E * 4);                            // arrival rank
    int* cnt = (int*)carve((size_t)N * 4);                             // zeroed in prep_w
    float* dis = (float*)carve((size_t)N * 4);
    int* offs = (int*)carve((size_t)(N + 1) * 4);
    float* scale1 = (float*)carve(D * 4);
    float* shift1 = (float*)carve(D * 4);
    float* scale2 = (float*)carve(D * 4);
    float* shift2 = (float*)carve(D * 4);
    unsigned short* WT1b = (unsigned short*)carve((size_t)D * D * 2);
    unsigned short* WT2b = (unsigned short*)carve((size_t)D * D * 2);
    float* pS = (float*)carve((size_t)AGG_GRID * D * 4);
    float* pQ = (float*)carve((size_t)AGG_GRID * D * 4);
    float* gm = (float*)carve((size_t)G * 4);
    float* gs = (float*)carve((size_t)G * 4);
    int* gb = (int*)carve((size_t)(G + 1) * 4);
    (void)ws_size;
    (void)n_in;

    // ---- W -> bf16 transposed + cnt zeroing ----
    prep_w<<<2 * D, D, 0, stream>>>(W1, W2, WT1b, WT2b, cnt, N);

    // ---- hist (atomic) + layer-1 BN stats (gather) + per-graph softmax stats ----
    int HB = cdiv(E, 256);
    hist_bn_kernel<<<HB + BN_GRID + G, 256, 0, stream>>>(ei_col, cnt, rank, E, emb, x_index,
                                                         pS, pQ, N, HB, BN_GRID, tfidf,
                                                         batch, gm, gs, gb, G);
    // ---- scan (offs) overlapped with layer-1 BN reduce (pS/pQ complete) ----
    int nb = cdiv(N, 1024);
    scan_bnred_kernel<<<nb + D, 1024, 0, stream>>>(cnt, offs, N, E, nb, pS, pQ, BN_GRID,
                                                   gamma1, beta1, scale1, shift1, (float)N);
    scatter_pack<<<cdiv(E, 256), 256, 0, stream>>>(ei_row, ei_col, edge_attr, rank, offs, pk,
                                                   E);
    sort_deg_kernel<<<cdiv(N, 16), 256, 0, stream>>>(pk, offs, dis, csr, N);

    // ---- layer 1 ----
    gemm_mfma<true, false><<<cdiv(N, 64), 256, 0, stream>>>(emb, x_index, scale1, shift1, WT1b,
                                                            dis, bufA, N);
    agg_kernel<true><<<AGG_GRID, 256, 0, stream>>>((const uint2*)bufA, csr, offs, dis,
                                                   (const float4*)b1, bufB, N, pS, pQ,
                                                   AGG_GRID);

    // ---- layer 2 ----
    bn_reduce<<<D, 256, 0, stream>>>(pS, pQ, AGG_GRID, gamma2, beta2, scale2, shift2, (float)N);
    gemm_mfma<false, true><<<cdiv(N, 64), 256, 0, stream>>>(bufB, nullptr, scale2, shift2,
                                                            WT2b, dis, bufA, N);
    agg_kernel<false><<<cdiv(N, 8), 256, 0, stream>>>((const uint2*)bufA, csr, offs, dis,
                                                      (const float4*)b2, bufB, N, nullptr,
                                                      nullptr, 0);

    // ---- softmax pooling (bf16 x, precomputed stats) ----
    pool_kernel<<<G, 1024, 0, stream>>>(tfidf, gb, gm, gs, bufB, out);
}